// Round 10
// baseline (91.080 us; speedup 1.0000x reference)
//
#include <hip/hip_runtime.h>

using bf16x8   = __attribute__((ext_vector_type(8))) __bf16;
using f32x4    = __attribute__((ext_vector_type(4))) float;
using f32x16   = __attribute__((ext_vector_type(16))) float;
using floatv4  = __attribute__((ext_vector_type(4))) float;
using ushortv4 = __attribute__((ext_vector_type(4))) unsigned short;
using ushortv8 = __attribute__((ext_vector_type(8))) unsigned short;
using uintv4   = __attribute__((ext_vector_type(4))) unsigned int;

#define N_SEQ 4096
#define N_B   4
#define DIMK  1024
#define HS    128
#define ROWS  (N_B * N_SEQ)
#define KVB   32
#define TT    (N_SEQ / KVB)   // 128 kv tiles
#define CEXPF 0.045084220027780106f   // log2(e)/32

__device__ __forceinline__ unsigned short f2bf(float f) {
    unsigned u = __builtin_bit_cast(unsigned, f);
    u += 0x7FFFu + ((u >> 16) & 1u);   // RNE
    return (unsigned short)(u >> 16);
}

__device__ __forceinline__ unsigned cvtpk(float lo, float hi) {
    unsigned r;
    asm("v_cvt_pk_bf16_f32 %0, %1, %2" : "=v"(r) : "v"(lo), "v"(hi));
    return r;
}

__device__ __forceinline__ void gload16(const unsigned short* g, unsigned short* l) {
    __builtin_amdgcn_global_load_lds(
        (const __attribute__((address_space(1))) unsigned int*)g,
        (__attribute__((address_space(3))) unsigned int*)l, 16, 0, 0);
}

// ---------------- castw: W -> bf16 MFMA B-fragments, Wq pre-scaled ----------------
// Wf flat: [32 t][24 frag][64 lane][8 bf16]
// lane l of frag f at k-step t holds W[f*16 + (l&15)][t*32 + (l>>4)*8 .. +7]
__global__ __launch_bounds__(256) void castw_kernel(
    const float* __restrict__ Wq,
    const float* __restrict__ Wk,
    const float* __restrict__ Wv,
    unsigned short* __restrict__ Wf)
{
    const int g = blockIdx.x * 256 + threadIdx.x;   // [0, 49152)
    const int l = g & 63;
    const int f = (g >> 6) % 24;
    const int t = g / (64 * 24);
    const int gc = f * 16 + (l & 15);
    const int z = gc >> 7, col = gc & 127;
    const int k0 = t * 32 + (l >> 4) * 8;
    const float* src = (z == 0) ? Wq : (z == 1) ? Wk : Wv;
    const float s = (z == 0) ? CEXPF : 1.0f;
    floatv4 a = *reinterpret_cast<const floatv4*>(src + (size_t)col * DIMK + k0);
    floatv4 b = *reinterpret_cast<const floatv4*>(src + (size_t)col * DIMK + k0 + 4);
    ushortv8 o = { f2bf(a.x*s), f2bf(a.y*s), f2bf(a.z*s), f2bf(a.w*s),
                   f2bf(b.x*s), f2bf(b.y*s), f2bf(b.z*s), f2bf(b.w*s) };
    *reinterpret_cast<ushortv8*>(Wf + (size_t)g * 8) = o;
}

// ---------------- single-pass projection: 32 rows x 384 cols, W from registers ----------------
// grid 512, block 256 = 4 waves. Wave wv owns cols wv*96..+95 (6 frags).
// X fp32 staged via gload_lds, 2 buffers, one-ahead prefetch, __syncthreads per iter
// (R6/R7-proven sync discipline; no raw-barrier/counted-vmcnt tricks).
__global__ __launch_bounds__(256, 3) void proj_kernel(
    const float* __restrict__ X,
    const unsigned short* __restrict__ Wf,
    unsigned short* __restrict__ Qb,
    unsigned short* __restrict__ Kb,
    unsigned short* __restrict__ Vt)
{
    const int row0 = blockIdx.x * 32;
    __shared__ float Xs[2304];   // 2 bufs x [32 rows][8 slots x 4 f32] = 2048; +pad for Cs overlay
    const int tid = threadIdx.x;
    const int wv = tid >> 6, lane = tid & 63;
    const int lr = lane & 15, lg = lane >> 4;

    // staging: lane covers local row wv*8+(lane>>3); phys slot (lane&7) holds logical (lane&7)^(row&7)
    const int srow = wv * 8 + (lane >> 3);
    const float* xsrc = X + (size_t)(row0 + srow) * DIMK + (((lane & 7) ^ (lane >> 3)) << 2);

    // ds_read float-offsets: logical slot q of row r at phys q^(r&7); row&7 == lr&7
    int offA[2], offB[2];
    #pragma unroll
    for (int mi = 0; mi < 2; ++mi) {
        offA[mi] = (mi * 16 + lr) * 32 + ((((lg << 1)    ) ^ (lr & 7)) << 2);
        offB[mi] = (mi * 16 + lr) * 32 + ((((lg << 1) | 1) ^ (lr & 7)) << 2);
    }

    // W fragment running pointer: frags wv*6+ni, lane-contiguous
    const unsigned short* wft = Wf + ((size_t)(wv * 6) * 64 + lane) * 8;

    f32x4 acc[2][6] = {};

    // stage tile 0; full drain
    gload16(reinterpret_cast<const unsigned short*>(xsrc),
            reinterpret_cast<unsigned short*>(Xs + wv * 256));
    __syncthreads();

    for (int t = 0; t < 32; ++t) {
        const int cur = t & 1;
        // prefetch next X tile (async; drained by this iter's trailing __syncthreads)
        if (t + 1 < 32)
            gload16(reinterpret_cast<const unsigned short*>(xsrc + (size_t)(t + 1) * 32),
                    reinterpret_cast<unsigned short*>(Xs + (cur ^ 1) * 1024 + wv * 256));

        // W fragments for this k-step (L2-resident, coalesced 1KB/wave per frag)
        bf16x8 bfr[6];
        #pragma unroll
        for (int ni = 0; ni < 6; ++ni)
            bfr[ni] = *reinterpret_cast<const bf16x8*>(wft + ni * 512);

        // A fragments from LDS (fp32 -> bf16)
        const float* Xc = Xs + cur * 1024;
        bf16x8 af[2];
        #pragma unroll
        for (int mi = 0; mi < 2; ++mi) {
            f32x4 a = *reinterpret_cast<const f32x4*>(Xc + offA[mi]);
            f32x4 b = *reinterpret_cast<const f32x4*>(Xc + offB[mi]);
            uintv4 w = { cvtpk(a.x, a.y), cvtpk(a.z, a.w),
                         cvtpk(b.x, b.y), cvtpk(b.z, b.w) };
            af[mi] = __builtin_bit_cast(bf16x8, w);
        }

        #pragma unroll
        for (int mi = 0; mi < 2; ++mi)
            #pragma unroll
            for (int ni = 0; ni < 6; ++ni)
                acc[mi][ni] = __builtin_amdgcn_mfma_f32_16x16x32_bf16(
                    af[mi], bfr[ni], acc[mi][ni], 0, 0, 0);

        wft += 12288;
        __syncthreads();   // drains prefetch (vmcnt 0) + all waves done with buf cur
    }

    // ---- epilogue: Q/K direct stores, V via LDS transpose ----
    unsigned short* Cs = reinterpret_cast<unsigned short*>(Xs);   // [32][136] = 8704B <= 9216B
    #pragma unroll
    for (int ni = 0; ni < 6; ++ni) {
        const int gc = wv * 96 + ni * 16;
        const int z = gc >> 7;
        const int col = (gc & 127) + lr;
        if (z < 2) {
            unsigned short* O = (z == 0) ? Qb : Kb;
            #pragma unroll
            for (int mi = 0; mi < 2; ++mi) {
                int rowb = row0 + mi * 16 + lg * 4;
                #pragma unroll
                for (int r = 0; r < 4; ++r)
                    O[(size_t)(rowb + r) * HS + col] = f2bf(acc[mi][ni][r]);
            }
        } else {
            #pragma unroll
            for (int mi = 0; mi < 2; ++mi)
                #pragma unroll
                for (int r = 0; r < 4; ++r)
                    Cs[(mi * 16 + lg * 4 + r) * 136 + col] = f2bf(acc[mi][ni][r]);
        }
    }
    __syncthreads();
    {
        const int b  = row0 >> 12;
        const int n0 = row0 & (N_SEQ - 1);
        #pragma unroll
        for (int i = 0; i < 2; ++i) {
            int idx = tid + i * 256;          // [0,512): 128 d x 4 chunks of 8 n
            int d = idx >> 2, c8 = idx & 3;
            ushortv8 v;
            #pragma unroll
            for (int j = 0; j < 8; ++j)
                v[j] = Cs[(c8 * 8 + j) * 136 + d];
            *reinterpret_cast<ushortv8*>(Vt + (size_t)b * HS * N_SEQ + (size_t)d * N_SEQ + n0 + c8 * 8) = v;
        }
    }
}

// ---------------- flash attention: counted-vmcnt 3-buffer, split-st, VALU lsum ----------------
// grid (128, S), block 256 = 4 waves, 32 q-rows/wave. LDS = 3x(K 8KB + V 8KB) = 48 KB.
__global__ __launch_bounds__(256, 3) void attn_kernel(
    const unsigned short* __restrict__ Qb,
    const unsigned short* __restrict__ Kb,
    const unsigned short* __restrict__ Vt,
    unsigned short* __restrict__ part,   // [512][S][32][128] bf16
    float* __restrict__ plsum,           // [512][S][32]
    int S)
{
    const int qblk  = blockIdx.x;      // [0,128)
    const int split = blockIdx.y;      // [0,S)
    const int tid = threadIdx.x;
    const int wv = tid >> 6, lane = tid & 63;
    const int l31 = lane & 31, h = lane >> 5;
    const int b    = qblk >> 5;
    const int row0 = (qblk & 31) * 128 + wv * 32;

    __shared__ unsigned short Ks[3][KVB * 128];   // [kv][hd], slot16 ^= (kv&7)
    __shared__ unsigned short Vs[3][128 * KVB];   // [d][kv],  slot4  ^= ((d>>1)&3)

    // Q as B-fragment (pre-scaled by log2(e)/32 via castw)
    bf16x8 qf[8];
    {
        const unsigned short* qp = Qb + ((size_t)b * N_SEQ + row0 + l31) * HS + h * 8;
        #pragma unroll
        for (int kk = 0; kk < 8; ++kk)
            qf[kk] = *reinterpret_cast<const bf16x8*>(qp + kk * 16);
    }

    const int base = TT / S, rem = TT % S;
    const int nt = base + (split < rem ? 1 : 0);
    const int kv_begin = (split * base + (split < rem ? split : rem)) * KVB;

    const unsigned short* Kbb = Kb + (size_t)b * N_SEQ * HS;
    const unsigned short* Vbb = Vt + (size_t)b * HS * N_SEQ;

    auto stage = [&](int buf, int kv0) {
        #pragma unroll
        for (int i = 0; i < 2; ++i) {          // K [32][128]
            int g = wv * 2 + i;
            int r = g * 4 + (lane >> 4);
            int sp = (lane & 15) ^ (r & 7);
            gload16(Kbb + (size_t)(kv0 + r) * HS + sp * 8, &Ks[buf][g * 4 * 128]);
        }
        #pragma unroll
        for (int i = 0; i < 2; ++i) {          // V^T [128][32]
            int g = wv * 2 + i;
            int r = g * 16 + (lane >> 2);
            int sp = (lane & 3) ^ ((r >> 1) & 3);
            gload16(Vbb + (size_t)r * N_SEQ + kv0 + sp * 8, &Vs[buf][g * 16 * KVB]);
        }
    };

    f32x16 ctx[4] = {};
    float lsum = 0.f;

    stage(0, kv_begin);
    stage(1, kv_begin + KVB);
    int cur = 0, nxt = 2;
    for (int t = 0; t < nt; ++t) {
        if (t + 2 < nt) {
            asm volatile("s_waitcnt vmcnt(4)\n\ts_barrier" ::: "memory");
            stage(nxt, kv_begin + (t + 2) * KVB);
        } else if (t + 1 < nt) {
            asm volatile("s_waitcnt vmcnt(4)\n\ts_barrier" ::: "memory");
        } else {
            asm volatile("s_waitcnt vmcnt(0)\n\ts_barrier" ::: "memory");
        }

        // S^T = K Q^T (swapped), two independent accumulator chains
        f32x16 st0 = {}, st1 = {};
        __builtin_amdgcn_s_setprio(1);
        #pragma unroll
        for (int kk = 0; kk < 8; kk += 2) {
            bf16x8 kf0 = *reinterpret_cast<const bf16x8*>(
                &Ks[cur][l31 * 128 + (((kk * 2 + h) ^ (l31 & 7)) * 8)]);
            st0 = __builtin_amdgcn_mfma_f32_32x32x16_bf16(kf0, qf[kk], st0, 0, 0, 0);
            bf16x8 kf1 = *reinterpret_cast<const bf16x8*>(
                &Ks[cur][l31 * 128 + ((((kk + 1) * 2 + h) ^ (l31 & 7)) * 8)]);
            st1 = __builtin_amdgcn_mfma_f32_32x32x16_bf16(kf1, qf[kk + 1], st1, 0, 0, 0);
        }
        __builtin_amdgcn_s_setprio(0);

        float p[16];
        #pragma unroll
        for (int r = 0; r < 16; ++r)
            p[r] = __builtin_amdgcn_exp2f(st0[r] + st1[r]);

        {
            float a0 = (p[0] + p[1])   + (p[2] + p[3]);
            float a1 = (p[4] + p[5])   + (p[6] + p[7]);
            float a2 = (p[8] + p[9])   + (p[10] + p[11]);
            float a3 = (p[12] + p[13]) + (p[14] + p[15]);
            lsum += (a0 + a1) + (a2 + a3);
        }

        bf16x8 pf[2];
        #pragma unroll
        for (int half = 0; half < 2; ++half) {
            unsigned a  = cvtpk(p[half*8 + 0], p[half*8 + 1]);
            unsigned bq = cvtpk(p[half*8 + 2], p[half*8 + 3]);
            unsigned c  = cvtpk(p[half*8 + 4], p[half*8 + 5]);
            unsigned d  = cvtpk(p[half*8 + 6], p[half*8 + 7]);
            asm("v_permlane32_swap_b32 %0, %1" : "+v"(a), "+v"(c));
            asm("v_permlane32_swap_b32 %0, %1" : "+v"(bq), "+v"(d));
            uintv4 w = { a, bq, c, d };
            pf[half] = __builtin_bit_cast(bf16x8, w);
        }

        __builtin_amdgcn_s_setprio(1);
        #pragma unroll
        for (int dt = 0; dt < 4; ++dt) {
            int d = dt * 32 + l31;
            bf16x8 vf0 = *reinterpret_cast<const bf16x8*>(
                &Vs[cur][d * KVB + (((0 + h) ^ ((d >> 1) & 3)) * 8)]);
            ctx[dt] = __builtin_amdgcn_mfma_f32_32x32x16_bf16(pf[0], vf0, ctx[dt], 0, 0, 0);
            bf16x8 vf1 = *reinterpret_cast<const bf16x8*>(
                &Vs[cur][d * KVB + (((2 + h) ^ ((d >> 1) & 3)) * 8)]);
            ctx[dt] = __builtin_amdgcn_mfma_f32_32x32x16_bf16(pf[1], vf1, ctx[dt], 0, 0, 0);
        }
        __builtin_amdgcn_s_setprio(0);

        cur = (cur == 2) ? 0 : cur + 1;
        nxt = (nxt == 2) ? 0 : nxt + 1;
    }

    lsum += __shfl_xor(lsum, 32);

    const int qt = qblk * 4 + wv;              // [0,512) 32-row tile
    unsigned short* pp = part + ((size_t)qt * S + split) * (32 * 128);
    #pragma unroll
    for (int rp = 0; rp < 4; ++rp)
        #pragma unroll
        for (int rq = 0; rq < 4; ++rq) {
            const int r = rp * 4 + rq;
            const int q = rq + 8 * rp + 4 * h;
            #pragma unroll
            for (int dt = 0; dt < 4; ++dt)
                pp[q * 128 + dt * 32 + l31] = (unsigned short)(cvtpk(ctx[dt][r], ctx[dt][r]) & 0xFFFFu);
        }
    if (h == 0)
        plsum[((size_t)qt * S + split) * 32 + l31] = lsum;
}

// combine KV-split partials: out = (sum_s part_s) / (sum_s lsum_s)
__global__ __launch_bounds__(256) void reduce_kernel(
    const unsigned short* __restrict__ part,
    const float* __restrict__ plsum,
    float* __restrict__ out, int S)
{
    const int id = blockIdx.x * 256 + threadIdx.x;   // [0, 16384*128/4)
    const int d4 = (id & 31) * 4;
    const int grow = id >> 5;                        // global q row
    const int qt = grow >> 5, q = grow & 31;
    f32x4 c = {0.f, 0.f, 0.f, 0.f};
    float l = 0.f;
    for (int s = 0; s < S; ++s) {
        ushortv4 pv = *reinterpret_cast<const ushortv4*>(
            &part[(((size_t)qt * S + s) * 32 + q) * 128 + d4]);
        #pragma unroll
        for (int j = 0; j < 4; ++j)
            c[j] += __builtin_bit_cast(float, (unsigned)pv[j] << 16);
        l += plsum[((size_t)qt * S + s) * 32 + q];
    }
    float inv = 1.0f / l;
    f32x4 o = { c[0]*inv, c[1]*inv, c[2]*inv, c[3]*inv };
    *reinterpret_cast<f32x4*>(&out[(size_t)grow * 128 + d4]) = o;
}

extern "C" void kernel_launch(void* const* d_in, const int* in_sizes, int n_in,
                              void* d_out, int out_size, void* d_ws, size_t ws_size,
                              hipStream_t stream) {
    const float* x  = (const float*)d_in[0];
    const float* wq = (const float*)d_in[1];
    const float* wk = (const float*)d_in[2];
    const float* wv = (const float*)d_in[3];

    // ws layout: Wf | Qb | Kb | Vt | plsum(max S) | part
    unsigned short* Wf = (unsigned short*)d_ws;                 // 0.79 MB
    unsigned short* Qb = Wf + (size_t)3 * HS * DIMK;
    unsigned short* Kb = Qb + (size_t)ROWS * HS;
    unsigned short* Vt = Kb + (size_t)ROWS * HS;
    float* plsum = (float*)(Vt + (size_t)N_B * HS * N_SEQ);

    const size_t fixed = (size_t)3 * HS * DIMK * 2 + (size_t)3 * ROWS * HS * 2;  // 13.4 MB
    const size_t per_split = (size_t)512 * 32 * 4 + (size_t)512 * 32 * 128 * 2;  // 4.26 MB

    int S;
    if      (ws_size >= fixed + 6 * per_split) S = 6;
    else if (ws_size >= fixed + 4 * per_split) S = 4;
    else if (ws_size >= fixed + 2 * per_split) S = 2;
    else                                       S = 1;

    unsigned short* part = (unsigned short*)(plsum + (size_t)512 * S * 32);

    castw_kernel<<<192, 256, 0, stream>>>(wq, wk, wv, Wf);
    proj_kernel<<<512, 256, 0, stream>>>(x, Wf, Qb, Kb, Vt);
    attn_kernel<<<dim3(128, S), 256, 0, stream>>>(Qb, Kb, Vt, part, plsum, S);
    reduce_kernel<<<(ROWS * HS) / 1024, 256, 0, stream>>>(part, plsum, (float*)d_out, S);
}